// Round 5
// baseline (114.852 us; speedup 1.0000x reference)
//
#include <hip/hip_runtime.h>
#include <hip/hip_cooperative_groups.h>
#include <math.h>

namespace cg = cooperative_groups;

constexpr int B    = 512;
constexpr int NIN  = 1024;
constexpr int NK   = 128;
constexpr int DK   = 5;
constexpr int NF   = NK * DK;     // 640 flattened kernel columns
constexpr int NOUT = NIN + NK;    // 1152
constexpr int SPLITK = 4;         // K chunks (256 each)
constexpr int LDA = 88;           // LDS row stride in halves (176B, 16B-aligned,
                                  // conflict-free for b128 fragment reads)
#define LOG2E 1.44269504088896f

typedef _Float16 f16x4 __attribute__((ext_vector_type(4)));
typedef _Float16 f16x8 __attribute__((ext_vector_type(8)));
typedef float    f32x4 __attribute__((ext_vector_type(4)));

// ---------------------------------------------------------------------------
// One cooperative kernel, 512 blocks x 256 threads (2 blocks/CU):
//  phase 1a (bid<320): split-K MFMA GEMM, LDS-staged, f32->f16 in-block.
//           tile=bid>>2 (10 n-tiles x 8 b-tiles), z=bid&3 (K chunk of 256).
//           actvP[z][n][b] partials + ps[z][n] theta^2 partials (b0==0 blocks).
//  phase 1b (bid>=320): x passthrough rows into out.
//  grid.sync()
//  phase 2 (all): pairwise f[b,k] for k=bid>>2, q=bid&3.
// ---------------------------------------------------------------------------
__global__ __launch_bounds__(256) void fused_kernel(
        const float* __restrict__ x,       // [512][1024]
        const float* __restrict__ theta,   // [1024][640]
        const float* __restrict__ lws,     // [640]
        const float* __restrict__ bias,    // [128]
        float* __restrict__ out,           // [512][1152]
        float* __restrict__ actvP,         // [4][640][512]
        float* __restrict__ ps) {          // [4][640]
    __shared__ _Float16 Ath[64 * LDA];     // theta^T tile [n][k]
    __shared__ _Float16 Bxh[64 * LDA];     // x tile [b][k]
    __shared__ float    red2[16][64];
    __shared__ float    a[DK * B];         // [5][512]
    __shared__ float    red[4 * 128];
    __shared__ float    s_sh[DK];
    __shared__ float    red_ps[DK * SPLITK];

    const int t   = threadIdx.x;
    const int bid = blockIdx.x;

    if (bid < 320) {
        // ---------------- GEMM phase ----------------
        const int tile = bid >> 2;
        const int z    = bid & 3;
        const int n0   = (tile >> 3) * 64;
        const int b0   = (tile & 7) * 64;
        const bool do_ps = (tile & 7) == 0;

        const int w   = t >> 6;            // wave id: n-subtile
        const int l   = t & 63;
        const int r16 = l & 15;
        const int kg  = l >> 4;
        const int tk4 = t >> 4;            // staging: k group of 4 (theta)
        const int tn4 = (t & 15) * 4;      // staging: col group of 4

        f32x4 acc0 = {0.f,0.f,0.f,0.f}, acc1 = {0.f,0.f,0.f,0.f};
        f32x4 acc2 = {0.f,0.f,0.f,0.f}, acc3 = {0.f,0.f,0.f,0.f};
        float sq0 = 0.f, sq1 = 0.f, sq2 = 0.f, sq3 = 0.f;

        for (int step = 0; step < 4; ++step) {
            const int kw = z * 256 + step * 64;
            // stage theta: read [4k x 4n] f32, transpose -> Ath[n][k] f16
            const float4 v0 = *(const float4*)&theta[(kw + tk4*4 + 0)*NF + n0 + tn4];
            const float4 v1 = *(const float4*)&theta[(kw + tk4*4 + 1)*NF + n0 + tn4];
            const float4 v2 = *(const float4*)&theta[(kw + tk4*4 + 2)*NF + n0 + tn4];
            const float4 v3 = *(const float4*)&theta[(kw + tk4*4 + 3)*NF + n0 + tn4];
            if (do_ps) {
                sq0 += v0.x*v0.x + v1.x*v1.x + v2.x*v2.x + v3.x*v3.x;
                sq1 += v0.y*v0.y + v1.y*v1.y + v2.y*v2.y + v3.y*v3.y;
                sq2 += v0.z*v0.z + v1.z*v1.z + v2.z*v2.z + v3.z*v3.z;
                sq3 += v0.w*v0.w + v1.w*v1.w + v2.w*v2.w + v3.w*v3.w;
            }
            {
                f16x4 h;
                h[0]=(_Float16)v0.x; h[1]=(_Float16)v1.x; h[2]=(_Float16)v2.x; h[3]=(_Float16)v3.x;
                *(f16x4*)&Ath[(tn4+0)*LDA + tk4*4] = h;
                h[0]=(_Float16)v0.y; h[1]=(_Float16)v1.y; h[2]=(_Float16)v2.y; h[3]=(_Float16)v3.y;
                *(f16x4*)&Ath[(tn4+1)*LDA + tk4*4] = h;
                h[0]=(_Float16)v0.z; h[1]=(_Float16)v1.z; h[2]=(_Float16)v2.z; h[3]=(_Float16)v3.z;
                *(f16x4*)&Ath[(tn4+2)*LDA + tk4*4] = h;
                h[0]=(_Float16)v0.w; h[1]=(_Float16)v1.w; h[2]=(_Float16)v2.w; h[3]=(_Float16)v3.w;
                *(f16x4*)&Ath[(tn4+3)*LDA + tk4*4] = h;
            }
            // stage x: rows already k-contiguous, no transpose
            #pragma unroll
            for (int i = 0; i < 4; ++i) {
                const int row = i * 16 + tk4;
                const float4 xv = *(const float4*)&x[(b0 + row)*NIN + kw + tn4];
                f16x4 h;
                h[0]=(_Float16)xv.x; h[1]=(_Float16)xv.y;
                h[2]=(_Float16)xv.z; h[3]=(_Float16)xv.w;
                *(f16x4*)&Bxh[row*LDA + tn4] = h;
            }
            __syncthreads();
            #pragma unroll
            for (int half = 0; half < 2; ++half) {
                const f16x8 av = *(const f16x8*)&Ath[(w*16 + r16)*LDA + kg*8 + half*32];
                const f16x8 bv0 = *(const f16x8*)&Bxh[( 0 + r16)*LDA + kg*8 + half*32];
                const f16x8 bv1 = *(const f16x8*)&Bxh[(16 + r16)*LDA + kg*8 + half*32];
                const f16x8 bv2 = *(const f16x8*)&Bxh[(32 + r16)*LDA + kg*8 + half*32];
                const f16x8 bv3 = *(const f16x8*)&Bxh[(48 + r16)*LDA + kg*8 + half*32];
                acc0 = __builtin_amdgcn_mfma_f32_16x16x32_f16(av, bv0, acc0, 0, 0, 0);
                acc1 = __builtin_amdgcn_mfma_f32_16x16x32_f16(av, bv1, acc1, 0, 0, 0);
                acc2 = __builtin_amdgcn_mfma_f32_16x16x32_f16(av, bv2, acc2, 0, 0, 0);
                acc3 = __builtin_amdgcn_mfma_f32_16x16x32_f16(av, bv3, acc3, 0, 0, 0);
            }
            __syncthreads();
        }
        // store partials: C map col=lane&15, row=(lane>>4)*4+reg [m89/m91]
        {
            float* dst = actvP + (size_t)z * NF * B
                       + (size_t)(n0 + w*16 + kg*4) * B + b0 + r16;
            #pragma unroll
            for (int j = 0; j < 4; ++j) {
                dst[j*B +  0] = acc0[j];
                dst[j*B + 16] = acc1[j];
                dst[j*B + 32] = acc2[j];
                dst[j*B + 48] = acc3[j];
            }
        }
        if (do_ps) {
            red2[tk4][tn4+0] = sq0; red2[tk4][tn4+1] = sq1;
            red2[tk4][tn4+2] = sq2; red2[tk4][tn4+3] = sq3;
            __syncthreads();
            if (t < 64) {
                float tot = 0.f;
                #pragma unroll
                for (int rr = 0; rr < 16; ++rr) tot += red2[rr][t];
                ps[z * NF + n0 + t] = tot;
            }
        }
    } else {
        // ---------------- x passthrough ----------------
        const int r0 = bid - 320;            // 0..191
        for (int row = r0; row < B; row += 192)
            ((float4*)out)[row * (NOUT/4) + t] = ((const float4*)x)[row * (NIN/4) + t];
    }

    cg::this_grid().sync();

    // ---------------- pairwise phase (all 512 blocks) ----------------
    const int k = bid >> 2;
    const int q = bid & 3;

    if (t < DK * SPLITK)
        red_ps[t] = ps[(t / DK) * NF + k * DK + (t % DK)];

    float regs[10];
    const float* base = actvP + (size_t)k * DK * B;
    #pragma unroll
    for (int j = 0; j < 10; ++j) {
        const int idx = t + 256 * j;
        float sum = 0.f;
        #pragma unroll
        for (int z = 0; z < SPLITK; ++z) sum += base[(size_t)z * NF * B + idx];
        regs[j] = sum;
    }
    __syncthreads();
    if (t < DK) {
        float sum = 0.f;
        #pragma unroll
        for (int c = 0; c < SPLITK; ++c) sum += red_ps[c * DK + t];
        s_sh[t] = __expf(lws[k * DK + t]) * rsqrtf(sum) * LOG2E;
    }
    __syncthreads();
    #pragma unroll
    for (int j = 0; j < 10; ++j)
        a[t + 256 * j] = regs[j] * s_sh[j >> 1];
    __syncthreads();

    const int g  = t >> 6;                 // wave-uniform b' quarter
    const int r  = t & 63;
    const int ba = q * 128 + r;
    const int bb = ba + 64;

    const float A0 = a[0*B + ba], A1 = a[1*B + ba], A2 = a[2*B + ba],
                A3 = a[3*B + ba], A4 = a[4*B + ba];
    const float B0 = a[0*B + bb], B1 = a[1*B + bb], B2 = a[2*B + bb],
                B3 = a[3*B + bb], B4 = a[4*B + bb];

    union F4 { float4 v; float f[4]; };

    float accA = 0.f, accB = 0.f;
    const int bp0 = g * 128;
    #pragma unroll 2
    for (int m = 0; m < 32; ++m) {
        const int bp = bp0 + 4 * m;        // wave-uniform -> LDS broadcast b128
        F4 w0, w1, w2, w3, w4;
        w0.v = *(const float4*)&a[0*B + bp];
        w1.v = *(const float4*)&a[1*B + bp];
        w2.v = *(const float4*)&a[2*B + bp];
        w3.v = *(const float4*)&a[3*B + bp];
        w4.v = *(const float4*)&a[4*B + bp];
        #pragma unroll
        for (int u = 0; u < 4; ++u) {
            const float dA = ((fabsf(A0 - w0.f[u]) + fabsf(A1 - w1.f[u]))
                            + (fabsf(A2 - w2.f[u]) + fabsf(A3 - w3.f[u])))
                            + fabsf(A4 - w4.f[u]);
            accA += __builtin_amdgcn_exp2f(-dA);
            const float dB = ((fabsf(B0 - w0.f[u]) + fabsf(B1 - w1.f[u]))
                            + (fabsf(B2 - w2.f[u]) + fabsf(B3 - w3.f[u])))
                            + fabsf(B4 - w4.f[u]);
            accB += __builtin_amdgcn_exp2f(-dB);
        }
    }
    red[g * 128 + r]      = accA;
    red[g * 128 + 64 + r] = accB;
    __syncthreads();
    if (t < 128) {
        const float f = ((red[0*128 + t] + red[1*128 + t])
                       + (red[2*128 + t] + red[3*128 + t]))
                       - 1.0f + bias[k];
        out[(q * 128 + t) * NOUT + NIN + k] = f;
    }
}

// ---------------------------------------------------------------------------
extern "C" void kernel_launch(void* const* d_in, const int* in_sizes, int n_in,
                              void* d_out, int out_size, void* d_ws, size_t ws_size,
                              hipStream_t stream) {
    const float* x     = (const float*)d_in[0];   // [512,1024]
    const float* theta = (const float*)d_in[1];   // [1024,128,5]
    const float* lws   = (const float*)d_in[2];   // [128,5]
    const float* bias  = (const float*)d_in[3];   // [128]
    float* out = (float*)d_out;                   // [512,1152]

    // ws layout: ps @0 (16KB pad), actvP @64KB (4 x 1.25MB)
    char* wsb = (char*)d_ws;
    float* ps    = (float*)wsb;
    float* actvP = (float*)(wsb + (64 << 10));

    void* args[] = {(void*)&x, (void*)&theta, (void*)&lws, (void*)&bias,
                    (void*)&out, (void*)&actvP, (void*)&ps};
    hipLaunchCooperativeKernel(reinterpret_cast<void*>(fused_kernel),
                               dim3(512), dim3(256), args, 0, stream);
}

// Round 6
// 27.789 us; speedup vs baseline: 4.1330x; 4.1330x over previous
//
#include <hip/hip_runtime.h>
#include <math.h>

constexpr int B    = 512;
constexpr int NIN  = 1024;
constexpr int NK   = 128;
constexpr int DK   = 5;
constexpr int NF   = NK * DK;     // 640 flattened kernel columns
constexpr int NOUT = NIN + NK;    // 1152
constexpr int SPLITK = 4;         // K chunks (256 each)
constexpr int LDA = 88;           // LDS row stride in halves
#define LOG2E 1.44269504088896f

typedef _Float16 f16x4 __attribute__((ext_vector_type(4)));
typedef _Float16 f16x8 __attribute__((ext_vector_type(8)));
typedef float    f32x4 __attribute__((ext_vector_type(4)));

// ---------------------------------------------------------------------------
// Kernel 1: split-K MFMA GEMM, f32->f16 staged in LDS (no prep pass).
//   grid 320 = 80 tiles (10n x 8b) x 4 z.  256 threads = 4 waves (n-subtiles).
//   actvP[z][n][b] partials; ps[z][n] theta^2 partials from b0==0 blocks.
// ---------------------------------------------------------------------------
__global__ __launch_bounds__(256) void gemm_kernel(
        const float* __restrict__ x,       // [512][1024]
        const float* __restrict__ theta,   // [1024][640]
        float* __restrict__ actvP,         // [4][640][512]
        float* __restrict__ ps) {          // [4][640]
    __shared__ _Float16 Ath[64 * LDA];     // theta^T tile [n][k]
    __shared__ _Float16 Bxh[64 * LDA];     // x tile [b][k]
    __shared__ float    red2[16][64];

    const int t    = threadIdx.x;
    const int tile = blockIdx.x >> 2;
    const int z    = blockIdx.x & 3;
    const int n0   = (tile >> 3) * 64;
    const int b0   = (tile & 7) * 64;
    const bool do_ps = (tile & 7) == 0;

    const int w   = t >> 6;            // wave id: n-subtile
    const int l   = t & 63;
    const int r16 = l & 15;
    const int kg  = l >> 4;
    const int tk4 = t >> 4;            // staging: k group of 4
    const int tn4 = (t & 15) * 4;      // staging: col group of 4

    f32x4 acc0 = {0.f,0.f,0.f,0.f}, acc1 = {0.f,0.f,0.f,0.f};
    f32x4 acc2 = {0.f,0.f,0.f,0.f}, acc3 = {0.f,0.f,0.f,0.f};
    float sq0 = 0.f, sq1 = 0.f, sq2 = 0.f, sq3 = 0.f;

    for (int step = 0; step < 4; ++step) {
        const int kw = z * 256 + step * 64;
        // stage theta: read [4k x 4n] f32, transpose -> Ath[n][k] f16
        const float4 v0 = *(const float4*)&theta[(kw + tk4*4 + 0)*NF + n0 + tn4];
        const float4 v1 = *(const float4*)&theta[(kw + tk4*4 + 1)*NF + n0 + tn4];
        const float4 v2 = *(const float4*)&theta[(kw + tk4*4 + 2)*NF + n0 + tn4];
        const float4 v3 = *(const float4*)&theta[(kw + tk4*4 + 3)*NF + n0 + tn4];
        if (do_ps) {
            sq0 += v0.x*v0.x + v1.x*v1.x + v2.x*v2.x + v3.x*v3.x;
            sq1 += v0.y*v0.y + v1.y*v1.y + v2.y*v2.y + v3.y*v3.y;
            sq2 += v0.z*v0.z + v1.z*v1.z + v2.z*v2.z + v3.z*v3.z;
            sq3 += v0.w*v0.w + v1.w*v1.w + v2.w*v2.w + v3.w*v3.w;
        }
        {
            f16x4 h;
            h[0]=(_Float16)v0.x; h[1]=(_Float16)v1.x; h[2]=(_Float16)v2.x; h[3]=(_Float16)v3.x;
            *(f16x4*)&Ath[(tn4+0)*LDA + tk4*4] = h;
            h[0]=(_Float16)v0.y; h[1]=(_Float16)v1.y; h[2]=(_Float16)v2.y; h[3]=(_Float16)v3.y;
            *(f16x4*)&Ath[(tn4+1)*LDA + tk4*4] = h;
            h[0]=(_Float16)v0.z; h[1]=(_Float16)v1.z; h[2]=(_Float16)v2.z; h[3]=(_Float16)v3.z;
            *(f16x4*)&Ath[(tn4+2)*LDA + tk4*4] = h;
            h[0]=(_Float16)v0.w; h[1]=(_Float16)v1.w; h[2]=(_Float16)v2.w; h[3]=(_Float16)v3.w;
            *(f16x4*)&Ath[(tn4+3)*LDA + tk4*4] = h;
        }
        // stage x: rows already k-contiguous
        #pragma unroll
        for (int i = 0; i < 4; ++i) {
            const int row = i * 16 + tk4;
            const float4 xv = *(const float4*)&x[(b0 + row)*NIN + kw + tn4];
            f16x4 h;
            h[0]=(_Float16)xv.x; h[1]=(_Float16)xv.y;
            h[2]=(_Float16)xv.z; h[3]=(_Float16)xv.w;
            *(f16x4*)&Bxh[row*LDA + tn4] = h;
        }
        __syncthreads();
        #pragma unroll
        for (int half = 0; half < 2; ++half) {
            const f16x8 av  = *(const f16x8*)&Ath[(w*16 + r16)*LDA + kg*8 + half*32];
            const f16x8 bv0 = *(const f16x8*)&Bxh[( 0 + r16)*LDA + kg*8 + half*32];
            const f16x8 bv1 = *(const f16x8*)&Bxh[(16 + r16)*LDA + kg*8 + half*32];
            const f16x8 bv2 = *(const f16x8*)&Bxh[(32 + r16)*LDA + kg*8 + half*32];
            const f16x8 bv3 = *(const f16x8*)&Bxh[(48 + r16)*LDA + kg*8 + half*32];
            acc0 = __builtin_amdgcn_mfma_f32_16x16x32_f16(av, bv0, acc0, 0, 0, 0);
            acc1 = __builtin_amdgcn_mfma_f32_16x16x32_f16(av, bv1, acc1, 0, 0, 0);
            acc2 = __builtin_amdgcn_mfma_f32_16x16x32_f16(av, bv2, acc2, 0, 0, 0);
            acc3 = __builtin_amdgcn_mfma_f32_16x16x32_f16(av, bv3, acc3, 0, 0, 0);
        }
        __syncthreads();
    }
    // store partials: C map col=lane&15, row=(lane>>4)*4+reg [m89/m91]
    {
        float* dst = actvP + (size_t)z * NF * B
                   + (size_t)(n0 + w*16 + kg*4) * B + b0 + r16;
        #pragma unroll
        for (int j = 0; j < 4; ++j) {
            dst[j*B +  0] = acc0[j];
            dst[j*B + 16] = acc1[j];
            dst[j*B + 32] = acc2[j];
            dst[j*B + 48] = acc3[j];
        }
    }
    if (do_ps) {
        red2[tk4][tn4+0] = sq0; red2[tk4][tn4+1] = sq1;
        red2[tk4][tn4+2] = sq2; red2[tk4][tn4+3] = sq3;
        __syncthreads();
        if (t < 64) {
            float tot = 0.f;
            #pragma unroll
            for (int rr = 0; rr < 16; ++rr) tot += red2[rr][t];
            ps[z * NF + n0 + t] = tot;
        }
    }
}

// ---------------------------------------------------------------------------
// Kernel 2: pairwise finish.  grid (128 k, 8 b-eighths) = 1024 blocks
// (4 blocks/CU, 4 waves/SIMD).  Each thread: 2 b-rows x 64 b' (g = t>>5).
//   s[d] = exp(lws)*rsqrt(sum ps)*log2e;  a = (sum_z actvP)*s
//   f[b,k] = sum_{b'} exp2(-sum_d |a-a'|) - 1 + bias[k]
//   blocks with e<4 also copy x row k*4+e into out.
// ---------------------------------------------------------------------------
__global__ __launch_bounds__(256) void pairwise_kernel(
        const float* __restrict__ actvP,   // [4][640][512]
        const float* __restrict__ ps,      // [4][640]
        const float* __restrict__ lws,     // [640]
        const float* __restrict__ bias,    // [128]
        const float* __restrict__ x,       // [512][1024]
        float* __restrict__ out) {         // [512][1152]
    __shared__ float a[DK * B];            // [5][512]
    __shared__ float red[8 * 64];
    __shared__ float s_sh[DK];
    __shared__ float red_ps[DK * SPLITK];

    const int k = blockIdx.x;
    const int e = blockIdx.y;              // b-eighth (0..7)
    const int t = threadIdx.x;

    // fused x passthrough: 4 of the 8 blocks per k copy one row each
    if (e < 4) {
        const int row = k * 4 + e;
        ((float4*)out)[row * (NOUT/4) + t] = ((const float4*)x)[row * (NIN/4) + t];
    }

    if (t < DK * SPLITK)
        red_ps[t] = ps[(t / DK) * NF + k * DK + (t % DK)];

    // split-K reduction into registers
    float regs[10];
    const float* base = actvP + (size_t)k * DK * B;
    #pragma unroll
    for (int j = 0; j < 10; ++j) {
        const int idx = t + 256 * j;
        float sum = 0.f;
        #pragma unroll
        for (int z = 0; z < SPLITK; ++z) sum += base[(size_t)z * NF * B + idx];
        regs[j] = sum;
    }
    __syncthreads();
    if (t < DK) {
        float sum = 0.f;
        #pragma unroll
        for (int c = 0; c < SPLITK; ++c) sum += red_ps[c * DK + t];
        s_sh[t] = __expf(lws[k * DK + t]) * rsqrtf(sum) * LOG2E;
    }
    __syncthreads();
    #pragma unroll
    for (int j = 0; j < 10; ++j)
        a[t + 256 * j] = regs[j] * s_sh[j >> 1];
    __syncthreads();

    const int g  = t >> 5;                 // wave-uniform b' eighth (0..7)
    const int r  = t & 31;
    const int ba = e * 64 + r;
    const int bb = ba + 32;

    const float A0 = a[0*B + ba], A1 = a[1*B + ba], A2 = a[2*B + ba],
                A3 = a[3*B + ba], A4 = a[4*B + ba];
    const float B0 = a[0*B + bb], B1 = a[1*B + bb], B2 = a[2*B + bb],
                B3 = a[3*B + bb], B4 = a[4*B + bb];

    union F4 { float4 v; float f[4]; };

    float accA = 0.f, accB = 0.f;
    const int bp0 = g * 64;
    #pragma unroll 4
    for (int m = 0; m < 16; ++m) {
        const int bp = bp0 + 4 * m;        // wave-uniform -> LDS broadcast b128
        F4 w0, w1, w2, w3, w4;
        w0.v = *(const float4*)&a[0*B + bp];
        w1.v = *(const float4*)&a[1*B + bp];
        w2.v = *(const float4*)&a[2*B + bp];
        w3.v = *(const float4*)&a[3*B + bp];
        w4.v = *(const float4*)&a[4*B + bp];
        #pragma unroll
        for (int u = 0; u < 4; ++u) {
            const float dA = ((fabsf(A0 - w0.f[u]) + fabsf(A1 - w1.f[u]))
                            + (fabsf(A2 - w2.f[u]) + fabsf(A3 - w3.f[u])))
                            + fabsf(A4 - w4.f[u]);
            accA += __builtin_amdgcn_exp2f(-dA);
            const float dB = ((fabsf(B0 - w0.f[u]) + fabsf(B1 - w1.f[u]))
                            + (fabsf(B2 - w2.f[u]) + fabsf(B3 - w3.f[u])))
                            + fabsf(B4 - w4.f[u]);
            accB += __builtin_amdgcn_exp2f(-dB);
        }
    }
    red[g * 64 + r]      = accA;
    red[g * 64 + 32 + r] = accB;
    __syncthreads();
    if (t < 64) {
        float f = -1.0f + bias[k];
        #pragma unroll
        for (int gg = 0; gg < 8; ++gg) f += red[gg * 64 + t];
        out[(e * 64 + t) * NOUT + NIN + k] = f;
    }
}

// ---------------------------------------------------------------------------
extern "C" void kernel_launch(void* const* d_in, const int* in_sizes, int n_in,
                              void* d_out, int out_size, void* d_ws, size_t ws_size,
                              hipStream_t stream) {
    const float* x     = (const float*)d_in[0];   // [512,1024]
    const float* theta = (const float*)d_in[1];   // [1024,128,5]
    const float* lws   = (const float*)d_in[2];   // [128,5]
    const float* bias  = (const float*)d_in[3];   // [128]
    float* out = (float*)d_out;                   // [512,1152]

    // ws layout: ps @0 (64KB pad), actvP @64KB (4 x 1.25MB)
    char* wsb = (char*)d_ws;
    float* ps    = (float*)wsb;
    float* actvP = (float*)(wsb + (64 << 10));

    gemm_kernel<<<dim3(320), 256, 0, stream>>>(x, theta, actvP, ps);
    pairwise_kernel<<<dim3(NK, 8), 256, 0, stream>>>(actvP, ps, lws, bias, x, out);
}

// Round 7
// 27.113 us; speedup vs baseline: 4.2361x; 1.0249x over previous
//
#include <hip/hip_runtime.h>
#include <hip/hip_fp16.h>
#include <math.h>

constexpr int B    = 512;
constexpr int NIN  = 1024;
constexpr int NK   = 128;
constexpr int DK   = 5;
constexpr int NF   = NK * DK;     // 640 flattened kernel columns
constexpr int NOUT = NIN + NK;    // 1152
constexpr int SPLITK = 4;         // K chunks (256 each)
constexpr int LDA = 88;           // LDS row stride in halves
#define LOG2E 1.44269504088896f

typedef _Float16 f16x2 __attribute__((ext_vector_type(2)));
typedef _Float16 f16x4 __attribute__((ext_vector_type(4)));
typedef _Float16 f16x8 __attribute__((ext_vector_type(8)));
typedef float    f32x4 __attribute__((ext_vector_type(4)));

union H2 { __half2 h; f16x2 v; unsigned u; };

// ---------------------------------------------------------------------------
// Kernel 1: split-K MFMA GEMM, f32->f16 staged in LDS (unchanged from R6).
//   grid 320 = 80 tiles (10n x 8b) x 4 z.  256 threads = 4 waves.
// ---------------------------------------------------------------------------
__global__ __launch_bounds__(256) void gemm_kernel(
        const float* __restrict__ x,       // [512][1024]
        const float* __restrict__ theta,   // [1024][640]
        float* __restrict__ actvP,         // [4][640][512]
        float* __restrict__ ps) {          // [4][640]
    __shared__ _Float16 Ath[64 * LDA];
    __shared__ _Float16 Bxh[64 * LDA];
    __shared__ float    red2[16][64];

    const int t    = threadIdx.x;
    const int tile = blockIdx.x >> 2;
    const int z    = blockIdx.x & 3;
    const int n0   = (tile >> 3) * 64;
    const int b0   = (tile & 7) * 64;
    const bool do_ps = (tile & 7) == 0;

    const int w   = t >> 6;
    const int l   = t & 63;
    const int r16 = l & 15;
    const int kg  = l >> 4;
    const int tk4 = t >> 4;
    const int tn4 = (t & 15) * 4;

    f32x4 acc0 = {0.f,0.f,0.f,0.f}, acc1 = {0.f,0.f,0.f,0.f};
    f32x4 acc2 = {0.f,0.f,0.f,0.f}, acc3 = {0.f,0.f,0.f,0.f};
    float sq0 = 0.f, sq1 = 0.f, sq2 = 0.f, sq3 = 0.f;

    for (int step = 0; step < 4; ++step) {
        const int kw = z * 256 + step * 64;
        const float4 v0 = *(const float4*)&theta[(kw + tk4*4 + 0)*NF + n0 + tn4];
        const float4 v1 = *(const float4*)&theta[(kw + tk4*4 + 1)*NF + n0 + tn4];
        const float4 v2 = *(const float4*)&theta[(kw + tk4*4 + 2)*NF + n0 + tn4];
        const float4 v3 = *(const float4*)&theta[(kw + tk4*4 + 3)*NF + n0 + tn4];
        if (do_ps) {
            sq0 += v0.x*v0.x + v1.x*v1.x + v2.x*v2.x + v3.x*v3.x;
            sq1 += v0.y*v0.y + v1.y*v1.y + v2.y*v2.y + v3.y*v3.y;
            sq2 += v0.z*v0.z + v1.z*v1.z + v2.z*v2.z + v3.z*v3.z;
            sq3 += v0.w*v0.w + v1.w*v1.w + v2.w*v2.w + v3.w*v3.w;
        }
        {
            f16x4 h;
            h[0]=(_Float16)v0.x; h[1]=(_Float16)v1.x; h[2]=(_Float16)v2.x; h[3]=(_Float16)v3.x;
            *(f16x4*)&Ath[(tn4+0)*LDA + tk4*4] = h;
            h[0]=(_Float16)v0.y; h[1]=(_Float16)v1.y; h[2]=(_Float16)v2.y; h[3]=(_Float16)v3.y;
            *(f16x4*)&Ath[(tn4+1)*LDA + tk4*4] = h;
            h[0]=(_Float16)v0.z; h[1]=(_Float16)v1.z; h[2]=(_Float16)v2.z; h[3]=(_Float16)v3.z;
            *(f16x4*)&Ath[(tn4+2)*LDA + tk4*4] = h;
            h[0]=(_Float16)v0.w; h[1]=(_Float16)v1.w; h[2]=(_Float16)v2.w; h[3]=(_Float16)v3.w;
            *(f16x4*)&Ath[(tn4+3)*LDA + tk4*4] = h;
        }
        #pragma unroll
        for (int i = 0; i < 4; ++i) {
            const int row = i * 16 + tk4;
            const float4 xv = *(const float4*)&x[(b0 + row)*NIN + kw + tn4];
            f16x4 h;
            h[0]=(_Float16)xv.x; h[1]=(_Float16)xv.y;
            h[2]=(_Float16)xv.z; h[3]=(_Float16)xv.w;
            *(f16x4*)&Bxh[row*LDA + tn4] = h;
        }
        __syncthreads();
        #pragma unroll
        for (int half = 0; half < 2; ++half) {
            const f16x8 av  = *(const f16x8*)&Ath[(w*16 + r16)*LDA + kg*8 + half*32];
            const f16x8 bv0 = *(const f16x8*)&Bxh[( 0 + r16)*LDA + kg*8 + half*32];
            const f16x8 bv1 = *(const f16x8*)&Bxh[(16 + r16)*LDA + kg*8 + half*32];
            const f16x8 bv2 = *(const f16x8*)&Bxh[(32 + r16)*LDA + kg*8 + half*32];
            const f16x8 bv3 = *(const f16x8*)&Bxh[(48 + r16)*LDA + kg*8 + half*32];
            acc0 = __builtin_amdgcn_mfma_f32_16x16x32_f16(av, bv0, acc0, 0, 0, 0);
            acc1 = __builtin_amdgcn_mfma_f32_16x16x32_f16(av, bv1, acc1, 0, 0, 0);
            acc2 = __builtin_amdgcn_mfma_f32_16x16x32_f16(av, bv2, acc2, 0, 0, 0);
            acc3 = __builtin_amdgcn_mfma_f32_16x16x32_f16(av, bv3, acc3, 0, 0, 0);
        }
        __syncthreads();
    }
    {
        float* dst = actvP + (size_t)z * NF * B
                   + (size_t)(n0 + w*16 + kg*4) * B + b0 + r16;
        #pragma unroll
        for (int j = 0; j < 4; ++j) {
            dst[j*B +  0] = acc0[j];
            dst[j*B + 16] = acc1[j];
            dst[j*B + 32] = acc2[j];
            dst[j*B + 48] = acc3[j];
        }
    }
    if (do_ps) {
        red2[tk4][tn4+0] = sq0; red2[tk4][tn4+1] = sq1;
        red2[tk4][tn4+2] = sq2; red2[tk4][tn4+3] = sq3;
        __syncthreads();
        if (t < 64) {
            float tot = 0.f;
            #pragma unroll
            for (int rr = 0; rr < 16; ++rr) tot += red2[rr][t];
            ps[z * NF + n0 + t] = tot;
        }
    }
}

// ---------------------------------------------------------------------------
// Kernel 2: split-K reduce + scale, once per n-row.
//   actv16[n][b] = f16( (sum_z actvP[z][n][b]) * exp(lws[n])*rsqrt(sum ps)*log2e )
// grid 320 x 256: block handles 2 n-rows, thread = (row half, 4 b-cols).
// ---------------------------------------------------------------------------
__global__ __launch_bounds__(256) void rs_kernel(
        const float* __restrict__ actvP,   // [4][640][512]
        const float* __restrict__ ps,      // [4][640]
        const float* __restrict__ lws,     // [640]
        __half* __restrict__ actv16) {     // [640][512]
    const int t   = threadIdx.x;
    const int row = blockIdx.x * 2 + (t >> 7);
    const int c4  = (t & 127) * 4;

    const float nrm = ps[0*NF + row] + ps[1*NF + row]
                    + ps[2*NF + row] + ps[3*NF + row];
    const float s = __expf(lws[row]) * rsqrtf(nrm) * LOG2E;

    const float* p = actvP + (size_t)row * B + c4;
    float4 v0 = *(const float4*)(p + 0ull * NF * B);
    float4 v1 = *(const float4*)(p + 1ull * NF * B);
    float4 v2 = *(const float4*)(p + 2ull * NF * B);
    float4 v3 = *(const float4*)(p + 3ull * NF * B);
    f16x4 h;
    h[0] = (_Float16)((v0.x + v1.x + v2.x + v3.x) * s);
    h[1] = (_Float16)((v0.y + v1.y + v2.y + v3.y) * s);
    h[2] = (_Float16)((v0.z + v1.z + v2.z + v3.z) * s);
    h[3] = (_Float16)((v0.w + v1.w + v2.w + v3.w) * s);
    *(f16x4*)&actv16[(size_t)row * B + c4] = h;
}

// ---------------------------------------------------------------------------
// Kernel 3: pairwise finish, packed f16.
//   f[b,k] = sum_{b'} exp2(-sum_d |a16[d,b]-a16[d,b']|) - 1 + bias[k]
// grid (128 k, 8 e) = 1024 blocks; 256 thr = 8 waves? no: 4 waves.
// thread: rows ba=e*64+(t&31), bb=ba+32; b' eighth g=t>>5 (64 b').
// ---------------------------------------------------------------------------
__global__ __launch_bounds__(256) void pairwise_kernel(
        const __half* __restrict__ actv16, // [640][512]
        const float* __restrict__ bias,    // [128]
        const float* __restrict__ x,       // [512][1024]
        float* __restrict__ out) {         // [512][1152]
    __shared__ __half a16s[DK * B];        // 5120 B
    __shared__ float  red[8 * 64];

    const int k = blockIdx.x;
    const int e = blockIdx.y;
    const int t = threadIdx.x;

    // fused x passthrough: 4 of the 8 blocks per k copy one row each
    if (e < 4) {
        const int row = k * 4 + e;
        ((float4*)out)[row * (NOUT/4) + t] = ((const float4*)x)[row * (NIN/4) + t];
    }

    // stage the k-slab (5 rows x 512 halves = 320 x 16B)
    {
        const uint4* src = (const uint4*)(actv16 + (size_t)k * DK * B);
        ((uint4*)a16s)[t] = src[t];
        if (t < 64) ((uint4*)a16s)[256 + t] = src[256 + t];
    }
    __syncthreads();

    const int g  = t >> 5;                 // wave-uniform b' eighth
    const int r  = t & 31;
    const int ba = e * 64 + r;
    const int bb = ba + 32;

    __half2 A2[DK], B2[DK];
    #pragma unroll
    for (int d = 0; d < DK; ++d) {
        A2[d] = __half2half2(a16s[d * B + ba]);
        B2[d] = __half2half2(a16s[d * B + bb]);
    }
    const H2 ones = {__half2half2(__float2half(1.0f))};

    float accA = 0.f, accB = 0.f;
    const int bp0 = g * 64;

    union W8 { f16x8 v; __half2 h[4]; };
    #pragma unroll 2
    for (int m = 0; m < 8; ++m) {
        const int bp = bp0 + m * 8;        // wave-uniform -> LDS b128 broadcast
        W8 w0, w1, w2, w3, w4;
        w0.v = *(const f16x8*)&a16s[0*B + bp];
        w1.v = *(const f16x8*)&a16s[1*B + bp];
        w2.v = *(const f16x8*)&a16s[2*B + bp];
        w3.v = *(const f16x8*)&a16s[3*B + bp];
        w4.v = *(const f16x8*)&a16s[4*B + bp];
        #pragma unroll
        for (int c = 0; c < 4; ++c) {
            __half2 dA = __habs2(__hsub2(A2[0], w0.h[c]));
            dA = __hadd2(dA, __habs2(__hsub2(A2[1], w1.h[c])));
            dA = __hadd2(dA, __habs2(__hsub2(A2[2], w2.h[c])));
            dA = __hadd2(dA, __habs2(__hsub2(A2[3], w3.h[c])));
            dA = __hadd2(dA, __habs2(__hsub2(A2[4], w4.h[c])));
            H2 eA; eA.h = h2exp2(__hneg2(dA));
            __half2 dB = __habs2(__hsub2(B2[0], w0.h[c]));
            dB = __hadd2(dB, __habs2(__hsub2(B2[1], w1.h[c])));
            dB = __hadd2(dB, __habs2(__hsub2(B2[2], w2.h[c])));
            dB = __hadd2(dB, __habs2(__hsub2(B2[3], w3.h[c])));
            dB = __hadd2(dB, __habs2(__hsub2(B2[4], w4.h[c])));
            H2 eB; eB.h = h2exp2(__hneg2(dB));
#if __has_builtin(__builtin_amdgcn_fdot2)
            accA = __builtin_amdgcn_fdot2(eA.v, ones.v, accA, false);
            accB = __builtin_amdgcn_fdot2(eB.v, ones.v, accB, false);
#else
            accA += __low2float(eA.h) + __high2float(eA.h);
            accB += __low2float(eB.h) + __high2float(eB.h);
#endif
        }
    }
    red[g * 64 + r]      = accA;
    red[g * 64 + 32 + r] = accB;
    __syncthreads();
    if (t < 64) {
        float f = -1.0f + bias[k];
        #pragma unroll
        for (int gg = 0; gg < 8; ++gg) f += red[gg * 64 + t];
        out[(e * 64 + t) * NOUT + NIN + k] = f;
    }
}

// ---------------------------------------------------------------------------
extern "C" void kernel_launch(void* const* d_in, const int* in_sizes, int n_in,
                              void* d_out, int out_size, void* d_ws, size_t ws_size,
                              hipStream_t stream) {
    const float* x     = (const float*)d_in[0];   // [512,1024]
    const float* theta = (const float*)d_in[1];   // [1024,128,5]
    const float* lws   = (const float*)d_in[2];   // [128,5]
    const float* bias  = (const float*)d_in[3];   // [128]
    float* out = (float*)d_out;                   // [512,1152]

    // ws layout: ps @0 (64KB pad), actvP @64KB (4 x 1.25MB), actv16 after
    char* wsb = (char*)d_ws;
    float*  ps     = (float*)wsb;
    float*  actvP  = (float*)(wsb + (64 << 10));
    __half* actv16 = (__half*)(wsb + (64 << 10) + 4 * sizeof(float) * NF * B);

    gemm_kernel<<<dim3(320), 256, 0, stream>>>(x, theta, actvP, ps);
    rs_kernel<<<dim3(320), 256, 0, stream>>>(actvP, ps, lws, actv16);
    pairwise_kernel<<<dim3(NK, 8), 256, 0, stream>>>(actv16, bias, x, out);
}